// Round 9
// baseline (261.221 us; speedup 1.0000x reference)
//
#include <hip/hip_runtime.h>
#include <cstdint>
#include <cstddef>

// ---------------------------------------------------------------------------
// DetCenterDense: fused conv3x3(128->64)+ReLU -> 4x conv1x1 heads (20 ch total,
// sigmoid on last 4) over [4,128,512,512] fp32, NCHW. bf16 MFMA implicit GEMM.
// R9: R7 schedule (12 waves/CU, B in LDS single-buf, 2 barriers/hc, counted
//     vmcnt(9)) with a 4x64 block tile (was 2x128): halo 2.0x -> 1.5x
//     (FETCH -24%), LDS staging -23%. Wave tile 2 rows x 32 cols x 64 och.
// ---------------------------------------------------------------------------

typedef __bf16 bf16x8 __attribute__((ext_vector_type(8)));
typedef float f32x16 __attribute__((ext_vector_type(16)));
typedef float f32x4v __attribute__((ext_vector_type(4)));
typedef float f32x2v __attribute__((ext_vector_type(2)));

#define CHW (512 * 512)

// A-tile LDS swizzle (validated R3-R8): granule 16B at (slot s, octet o):
//   lin = s*32 + o*16 ; byte = lin ^ ((lin>>1)&0x10) ^ ((lin>>2)&0x60)
__device__ __forceinline__ int swz(int s, int o) {
    int lin = (s << 5) | (o << 4);
    return lin ^ ((lin >> 1) & 0x10) ^ ((lin >> 2) & 0x60);
}

// ---------------------------------------------------------------------------
// Prepass: repack w_shared [64][128][3][3] fp32 -> bf16, per-half-chunk
// contiguous: ws3 [hc(8)][tap(9)][hw(2)][och(64)][8 bf16]  (18432 B per hc)
// ---------------------------------------------------------------------------
__global__ void prep_w_kernel(const float* __restrict__ w, __bf16* __restrict__ ws3) {
    int idx = blockIdx.x * 256 + threadIdx.x;
    if (idx >= 64 * 128 * 9) return;
    int tap = idx % 9;
    int cin = (idx / 9) % 128;
    int och = idx / (9 * 128);
    int hc = cin >> 4;
    int hw = (cin >> 3) & 1;
    int j  = cin & 7;
    int dst = (((hc * 9 + tap) * 2 + hw) * 64 + och) * 8 + j;
    ws3[dst] = (__bf16)w[idx];
}

// LDS map (bytes), total 48768 -> 3 blocks/CU:
//   A0 @ 0 [13056]  A1 @ 13056 [13056]   ([6 rows][68 slots x 32B], swz; slot
//                                          s <-> w = w0-1+s, used s=0..65)
//   B  @ 26112 [18432]  single buf: [tap 9][hw 2][och 64][8 bf16], linear
//   wc @ 44544 [4096]   bias @ 48640 [128]
//   X tile overlays @0 [32768] after the main loop.
#define A_OFF(p)   ((p) ? 13056 : 0)
#define AROW       2176
#define B_BASE     26112
#define WC_BASE    44544
#define BIAS_BASE  48640

__global__ __launch_bounds__(256, 3)
void det_main_kernel(const float* __restrict__ feature,
                     const __bf16* __restrict__ ws3,
                     const float* __restrict__ w_cls, const float* __restrict__ b_cls,
                     const float* __restrict__ w_box, const float* __restrict__ b_box,
                     const float* __restrict__ w_dir, const float* __restrict__ b_dir,
                     const float* __restrict__ w_scr, const float* __restrict__ b_scr,
                     float* __restrict__ out) {
    __shared__ __align__(1024) char s_all[48768];

    const int tid  = threadIdx.x;
    const int lane = tid & 63;
    const int wave = tid >> 6;
    const int l31  = lane & 31;
    const int hw   = lane >> 5;
    const int wrow2 = (wave >> 1) * 2;   // wave's first output row (0 or 2)
    const int wcb2  = (wave & 1) * 32;   // wave's col base (0 or 32)

    // XCD-aware decode: 4096 blocks -> 8 chunks of 512; within a chunk h_t
    // varies fastest so vertically-adjacent blocks (sharing halo rows) are
    // schedule-adjacent on one XCD.
    const int bid = blockIdx.x;
    const int wg  = (bid & 7) * 512 + (bid >> 3);
    const int h_t = wg & 127;
    const int rst = wg >> 7;          // 0..31
    const int bz  = rst >> 3;
    const int w_t = rst & 7;
    const int h0  = h_t * 4;
    const int w0  = w_t * 64;

    // ---- staging roles ----
    // main: thread (o = tid&1, q = (tid>>1)&15, r = tid>>5): 8 cin x 4 slots
    // at staged row r (r=6,7 are clamped dups, loads only, no writes).
    const int m_o  = tid & 1;
    const int m_q  = (tid >> 1) & 15;
    const int m_rr = tid >> 5;                     // 0..7
    const int m_r  = (m_rr < 6) ? m_rr : (m_rr - 6);
    const bool m_wr = (m_rr < 6);
    const int m_h  = h0 - 1 + m_r;
    const bool m_ok = (unsigned)m_h < 512u;
    const float* m_base = feature + (size_t)(bz * 128 + m_o * 8) * CHW
                        + (size_t)(m_ok ? m_h : 0) * 512 + (w0 + 4 * m_q);

    // edge: 192 tasks (side 2 x row 6 x cin 16), tids>=192 dup; one f32x2.
    const int e_t   = (tid < 192) ? tid : (tid - 64);
    const bool e_wr = (tid < 192);
    const int e_sd  = e_t / 96;                    // 0: w0-1 (slot 0), 1: w0+64 (slot 65)
    const int e_r   = (e_t % 96) >> 4;             // 0..5
    const int e_c   = e_t & 15;                    // cin 0..15
    const int e_h   = h0 - 1 + e_r;
    const bool e_ok = ((unsigned)e_h < 512u) && (e_sd ? (w0 + 64 < 512) : (w0 > 0));
    const int e_col = e_sd ? (w0 + 64) : (w0 - 2);
    const float* e_base = feature + (size_t)(bz * 128 + e_c) * CHW
                        + (size_t)(e_ok ? e_h : 0) * 512 + (e_ok ? e_col : 0);

    f32x4v R[8];      // 1-deep A prefetch (32 VGPR)
    f32x2v E;

    // issue A-loads for half-chunk hc: ALWAYS 9 vmem instrs per wave.
    auto issueA = [&](int hc) {
        const float* p = m_base + (size_t)(hc * 16) * CHW;
        #pragma unroll
        for (int j = 0; j < 8; ++j) R[j] = *(const f32x4v*)(p + (size_t)j * CHW);
        E = *(const f32x2v*)(e_base + (size_t)(hc * 16) * CHW);
    };

    // convert + ds_write into A-buf[hc&1]; zero OOB here (no vmem).
    auto writeA = [&](int hc) {
        char* ab = s_all + A_OFF(hc & 1);
        if (m_wr) {
            #pragma unroll
            for (int k = 0; k < 4; ++k) {
                bf16x8 g;
                #pragma unroll
                for (int j = 0; j < 8; ++j) g[j] = (__bf16)(m_ok ? R[j][k] : 0.f);
                *(bf16x8*)(ab + m_r * AROW + swz(1 + 4 * m_q + k, m_o)) = g;
            }
        }
        if (e_wr) {
            float v = e_sd ? E[0] : E[1];
            *(__bf16*)(ab + e_r * AROW + swz(e_sd ? 65 : 0, e_c >> 3) + (e_c & 7) * 2)
                = (__bf16)(e_ok ? v : 0.f);
        }
    };

    // async global->LDS of hc's weights (1152 x 16B): waves 0,1: 5; waves 2,3: 4.
    auto issueB = [&](int hc) {
        char* bb = s_all + B_BASE;
        const char* src = (const char*)ws3 + hc * 18432;
        #pragma unroll
        for (int i = 0; i < 4; ++i) {
            int g0 = i * 256 + wave * 64;
            __builtin_amdgcn_global_load_lds(
                (const __attribute__((address_space(1))) void*)(src + (size_t)(g0 + lane) * 16),
                (__attribute__((address_space(3))) void*)(bb + g0 * 16), 16, 0, 0);
        }
        if (wave < 2) {
            int g0 = 1024 + wave * 64;
            __builtin_amdgcn_global_load_lds(
                (const __attribute__((address_space(1))) void*)(src + (size_t)(g0 + lane) * 16),
                (__attribute__((address_space(3))) void*)(bb + g0 * 16), 16, 0, 0);
        }
    };

    // ---- stage 1x1-head weights + bias into LDS (once, at start) ----
    {
        char* s_wc = s_all + WC_BASE;
        float* s_bias = (float*)(s_all + BIAS_BASE);
        int och = tid >> 3;
        int j8  = (tid & 7) * 8;
        float v[8];
        if (och < 20) {
            const float* src = (och < 2)  ? (w_cls + och * 64)
                             : (och < 8)  ? (w_box + (och - 2) * 64)
                             : (och < 16) ? (w_dir + (och - 8) * 64)
                                          : (w_scr + (och - 16) * 64);
            #pragma unroll
            for (int j = 0; j < 8; ++j) v[j] = src[j8 + j];
        } else {
            #pragma unroll
            for (int j = 0; j < 8; ++j) v[j] = 0.f;
        }
        bf16x8 wv;
        #pragma unroll
        for (int j = 0; j < 8; ++j) wv[j] = (__bf16)v[j];
        *(bf16x8*)(s_wc + och * 128 + ((j8 * 2) ^ ((och & 7) << 4))) = wv;
        if (tid < 32) {
            s_bias[tid] = (tid < 2)  ? b_cls[tid]
                        : (tid < 8)  ? b_box[tid - 2]
                        : (tid < 16) ? b_dir[tid - 8]
                        : (tid < 20) ? b_scr[tid - 16] : 0.f;
        }
    }

    f32x16 zero16;
    #pragma unroll
    for (int e = 0; e < 16; ++e) zero16[e] = 0.f;
    f32x16 acc[2][2];
    acc[0][0] = zero16; acc[0][1] = zero16; acc[1][0] = zero16; acc[1][1] = zero16;

    auto mfma_phase = [&](int hc) {
        const char* ab = s_all + A_OFF(hc & 1);
        const char* bb = s_all + B_BASE;
        #pragma unroll
        for (int tap = 0; tap < 9; ++tap) {
            const int kh = tap / 3, kw = tap % 3;
            bf16x8 Bf0 = *(const bf16x8*)(bb + (size_t)((tap * 2 + hw) * 64 +      l31) * 16);
            bf16x8 Bf1 = *(const bf16x8*)(bb + (size_t)((tap * 2 + hw) * 64 + 32 + l31) * 16);
            const int sz = swz(wcb2 + l31 + kw, hw);
            bf16x8 Af0 = *(const bf16x8*)(ab + (wrow2 + 0 + kh) * AROW + sz);
            bf16x8 Af1 = *(const bf16x8*)(ab + (wrow2 + 1 + kh) * AROW + sz);
            __builtin_amdgcn_s_setprio(1);
            acc[0][0] = __builtin_amdgcn_mfma_f32_32x32x16_bf16(Af0, Bf0, acc[0][0], 0, 0, 0);
            acc[0][1] = __builtin_amdgcn_mfma_f32_32x32x16_bf16(Af0, Bf1, acc[0][1], 0, 0, 0);
            acc[1][0] = __builtin_amdgcn_mfma_f32_32x32x16_bf16(Af1, Bf0, acc[1][0], 0, 0, 0);
            acc[1][1] = __builtin_amdgcn_mfma_f32_32x32x16_bf16(Af1, Bf1, acc[1][1], 0, 0, 0);
            __builtin_amdgcn_s_setprio(0);
        }
    };

    // ---- prologue: B(0) DMA'd, A(0) staged, A(1) left in flight ----
    issueB(0);
    issueA(0);
    writeA(0);                     // reg-deps drain A(0); in-order => B(0) too
    issueA(1);
    __builtin_amdgcn_sched_barrier(0);
    asm volatile("s_waitcnt lgkmcnt(0)" ::: "memory");   // ds_writes visible
    __builtin_amdgcn_s_barrier();
    __builtin_amdgcn_sched_barrier(0);

    // ---- main loop: 8 half-chunks of 16 cin, 2 barriers each ----
    #pragma unroll 1
    for (int h = 0; h < 8; ++h) {
        mfma_phase(h);
        __builtin_amdgcn_sched_barrier(0);
        __builtin_amdgcn_s_barrier();            // bar1: A(h),B(h) readers done
        __builtin_amdgcn_sched_barrier(0);
        if (h == 7) break;
        issueB(h + 1);                           // overwrite B (safe after bar1)
        writeA(h + 1);                           // into A-buf[(h+1)&1]
        if (h < 6) issueA(h + 2);
        if (h < 6) asm volatile("s_waitcnt vmcnt(9) lgkmcnt(0)" ::: "memory");
        else       asm volatile("s_waitcnt vmcnt(0) lgkmcnt(0)" ::: "memory");
        __builtin_amdgcn_s_barrier();            // bar2: A(h+1),B(h+1) ready
        __builtin_amdgcn_sched_barrier(0);
    }

    // ---- ReLU -> bf16 X tile in LDS (overlay A/B region @0) ----
    __syncthreads();                             // all waves done with A/B bufs
    __bf16* X = (__bf16*)s_all;                  // [256 px][64 ch] = 32 KB
    #pragma unroll
    for (int mt = 0; mt < 2; ++mt) {
        #pragma unroll
        for (int nt = 0; nt < 2; ++nt) {
            #pragma unroll
            for (int r = 0; r < 16; ++r) {
                float v = fmaxf(acc[mt][nt][r], 0.f);
                int mpix = (r & 3) + 8 * (r >> 2) + 4 * hw;
                int px   = (wrow2 + mt) * 64 + wcb2 + mpix;
                int chn  = nt * 32 + l31;
                *(__bf16*)((char*)X + px * 128 + ((chn * 2) ^ ((px & 7) << 4))) = (__bf16)v;
            }
        }
    }
    // X is wave-local: wave reads exactly the px range it wrote.

    // ---- stage 2: out[och(20->32)][px] = Wc @ X, K=64 ----
    const char* s_wc = s_all + WC_BASE;
    const float* s_bias = (const float*)(s_all + BIAS_BASE);
    f32x16 acc2[2];
    acc2[0] = zero16; acc2[1] = zero16;
    #pragma unroll
    for (int ks = 0; ks < 4; ++ks) {
        int ch0 = ks * 16 + hw * 8;
        bf16x8 a2 = *(const bf16x8*)(s_wc + l31 * 128 + ((ch0 * 2) ^ ((l31 & 7) << 4)));
        #pragma unroll
        for (int pt = 0; pt < 2; ++pt) {
            int px = (wrow2 + pt) * 64 + wcb2 + l31;
            bf16x8 b2 = *(const bf16x8*)((const char*)X + px * 128 + ((ch0 * 2) ^ ((px & 7) << 4)));
            acc2[pt] = __builtin_amdgcn_mfma_f32_32x32x16_bf16(a2, b2, acc2[pt], 0, 0, 0);
        }
    }

    // ---- epilogue: bias, sigmoid on och 16..19, coalesced stores ----
    #pragma unroll
    for (int pt = 0; pt < 2; ++pt) {
        int hrow = h0 + wrow2 + pt;
        int wcol = w0 + wcb2 + l31;
        #pragma unroll
        for (int r = 0; r < 16; ++r) {
            int och = (r & 3) + 8 * (r >> 2) + 4 * hw;
            if (och < 20) {
                float v = acc2[pt][r] + s_bias[och];
                if (och >= 16) v = 1.f / (1.f + __expf(-v));
                out[(((size_t)bz * 20 + och) * 512 + hrow) * 512 + wcol] = v;
            }
        }
    }
}

extern "C" void kernel_launch(void* const* d_in, const int* in_sizes, int n_in,
                              void* d_out, int out_size, void* d_ws, size_t ws_size,
                              hipStream_t stream) {
    const float* feature  = (const float*)d_in[0];
    const float* w_shared = (const float*)d_in[1];
    const float* w_cls = (const float*)d_in[2];
    const float* b_cls = (const float*)d_in[3];
    const float* w_box = (const float*)d_in[4];
    const float* b_box = (const float*)d_in[5];
    const float* w_dir = (const float*)d_in[6];
    const float* b_dir = (const float*)d_in[7];
    const float* w_scr = (const float*)d_in[8];
    const float* b_scr = (const float*)d_in[9];
    float* out = (float*)d_out;
    __bf16* ws3 = (__bf16*)d_ws;   // 8 * 18432 B = 147456 B

    prep_w_kernel<<<288, 256, 0, stream>>>(w_shared, ws3);

    det_main_kernel<<<4096, 256, 0, stream>>>(feature, ws3,
                                              w_cls, b_cls, w_box, b_box,
                                              w_dir, b_dir, w_scr, b_scr, out);
}

// Round 10
// 245.077 us; speedup vs baseline: 1.0659x; 1.0659x over previous
//
#include <hip/hip_runtime.h>
#include <cstdint>
#include <cstddef>

// ---------------------------------------------------------------------------
// DetCenterDense: fused conv3x3(128->64)+ReLU -> 4x conv1x1 heads (20 ch total,
// sigmoid on last 4) over [4,128,512,512] fp32, NCHW. bf16 MFMA implicit GEMM.
// R10: occupancy push to 16 waves/CU. 512-thr blocks (8 waves), wave tile
//      32px x 64och (acc = 32 AGPR), same 2x128 block tile / A-swizzle /
//      B-DMA / 2-barrier schedule as R7. Staging 16 VGPR/thread. A-waits are
//      reg-dep; counted vmcnt only drains B-DMA (4 or 5 per wave role).
// ---------------------------------------------------------------------------

typedef __bf16 bf16x8 __attribute__((ext_vector_type(8)));
typedef __bf16 bf16x4 __attribute__((ext_vector_type(4)));
typedef float f32x16 __attribute__((ext_vector_type(16)));
typedef float f32x4v __attribute__((ext_vector_type(4)));

#define CHW (512 * 512)

// A-tile LDS swizzle (validated R3-R9): granule 16B at (slot s, octet o):
//   lin = s*32 + o*16 ; byte = lin ^ ((lin>>1)&0x10) ^ ((lin>>2)&0x60)
__device__ __forceinline__ int swz(int s, int o) {
    int lin = (s << 5) | (o << 4);
    return lin ^ ((lin >> 1) & 0x10) ^ ((lin >> 2) & 0x60);
}

// ---------------------------------------------------------------------------
// Prepass: repack w_shared [64][128][3][3] fp32 -> bf16, per-half-chunk
// contiguous: ws3 [hc(8)][tap(9)][hw(2)][och(64)][8 bf16]  (18432 B per hc)
// ---------------------------------------------------------------------------
__global__ void prep_w_kernel(const float* __restrict__ w, __bf16* __restrict__ ws3) {
    int idx = blockIdx.x * 256 + threadIdx.x;
    if (idx >= 64 * 128 * 9) return;
    int tap = idx % 9;
    int cin = (idx / 9) % 128;
    int och = idx / (9 * 128);
    int hc = cin >> 4;
    int hw = (cin >> 3) & 1;
    int j  = cin & 7;
    int dst = (((hc * 9 + tap) * 2 + hw) * 64 + och) * 8 + j;
    ws3[dst] = (__bf16)w[idx];
}

// LDS map (bytes), total 51712 (3 blocks by LDS; regs give 2 blocks = 16 waves):
//   A0 @ 0 [16640]  A1 @ 16640 [16640]  ([4 rows][130 slots x 32B], swizzled;
//                                        slot s <-> w = w0-1+s, s=0..129)
//   B  @ 33280 [18432]  single buf: [tap 9][hw 2][och 64][8 bf16], linear
//   wc overlays B @33280 [4096] post-loop; bias @37376 [128].
//   X tile overlays A @0 [32768] post-loop.
#define A_OFF(p)   ((p) ? 16640 : 0)
#define AROW       4160
#define B_BASE     33280
#define WC_BASE    33280
#define BIAS_BASE  37376

__global__ __launch_bounds__(512, 4)
void det_main_kernel(const float* __restrict__ feature,
                     const __bf16* __restrict__ ws3,
                     const float* __restrict__ w_cls, const float* __restrict__ b_cls,
                     const float* __restrict__ w_box, const float* __restrict__ b_box,
                     const float* __restrict__ w_dir, const float* __restrict__ b_dir,
                     const float* __restrict__ w_scr, const float* __restrict__ b_scr,
                     float* __restrict__ out) {
    __shared__ __align__(1024) char s_all[51712];

    const int tid  = threadIdx.x;
    const int lane = tid & 63;
    const int wave = tid >> 6;         // 0..7
    const int l31  = lane & 31;
    const int hw   = lane >> 5;
    const int wrow = wave >> 2;        // output row within tile (0..1)
    const int wcb  = (wave & 3) * 32;  // col base (0,32,64,96)

    // XCD-aware decode (R7-validated): 4096 blocks -> 8 chunks of 512.
    const int bid = blockIdx.x;
    const int wg  = (bid & 7) * 512 + (bid >> 3);
    const int ck  = wg >> 9;
    const int bz  = ck >> 1;
    const int rem = wg & 511;
    const int h0  = (rem >> 1) * 2;
    const int w0  = ((ck & 1) * 2 + (rem & 1)) * 128;

    // ---- staging roles ----
    // main (all 512): thread = (octet o, slot-quad q, row r, cin-half hf):
    //   4 cin x 4 slots -> 4 x f32x4 loads (w-contiguous), 4 x ds_write_b64.
    const int m_o  = tid & 1;
    const int m_q  = (tid >> 1) & 31;          // slots 1+4q .. 4+4q (w0..w0+127)
    const int m_r  = (tid >> 6) & 3;           // staged row 0..3
    const int m_hf = tid >> 8;                 // cin half within octet
    const int m_h  = h0 - 1 + m_r;
    const bool m_ok = (unsigned)m_h < 512u;
    const float* m_base = feature
        + (size_t)(bz * 128 + m_o * 8 + m_hf * 4) * CHW
        + (size_t)(m_ok ? m_h : 0) * 512 + (w0 + 4 * m_q);

    // edge (waves 2,3 = tid 128..255): slots 0 (w0-1) and 129 (w0+128):
    //   2 sides x 4 rows x 16 cin = 128 tasks, one scalar f32 load each.
    const bool e_on = (tid >= 128) && (tid < 256);
    const int e_t   = tid & 127;
    const int e_sd  = e_t >> 6;                // 0: w0-1, 1: w0+128
    const int e_r   = (e_t >> 4) & 3;
    const int e_c   = e_t & 15;
    const int e_h   = h0 - 1 + e_r;
    const bool e_ok = e_on && ((unsigned)e_h < 512u)
                    && (e_sd ? (w0 + 128 < 512) : (w0 > 0));
    const int e_col = e_sd ? (w0 + 128) : (w0 - 1);
    const float* e_base = feature + (size_t)(bz * 128 + e_c) * CHW
                        + (size_t)(e_ok ? e_h : 0) * 512 + (e_ok ? e_col : 0);

    f32x4v R[4];      // A prefetch: 4 cin x 4 w (16 VGPR)
    float  E;         // edge prefetch

    auto issueA = [&](int hc) {
        const float* p = m_base + (size_t)(hc * 16) * CHW;
        #pragma unroll
        for (int j = 0; j < 4; ++j) R[j] = *(const f32x4v*)(p + (size_t)j * CHW);
        if (e_on) E = *(e_base + (size_t)(hc * 16) * CHW);
    };

    auto writeA = [&](int hc) {
        char* ab = s_all + A_OFF(hc & 1);
        #pragma unroll
        for (int k = 0; k < 4; ++k) {
            bf16x4 g;
            #pragma unroll
            for (int j = 0; j < 4; ++j) g[j] = (__bf16)(m_ok ? R[j][k] : 0.f);
            *(bf16x4*)(ab + m_r * AROW + swz(1 + 4 * m_q + k, m_o) + m_hf * 8) = g;
        }
        if (e_on) {
            *(__bf16*)(ab + e_r * AROW + swz(e_sd ? 129 : 0, e_c >> 3) + (e_c & 7) * 2)
                = (__bf16)(e_ok ? E : 0.f);
        }
    };

    // B DMA: 18 chunks of 64 granules; waves 0,1 take 3 chunks, waves 2..7: 2.
    auto issueB = [&](int hc) {
        char* bb = s_all + B_BASE;
        const char* src = (const char*)ws3 + hc * 18432;
        if (wave < 2) {
            #pragma unroll
            for (int i = 0; i < 3; ++i) {
                int g0 = (wave * 3 + i) * 64;
                __builtin_amdgcn_global_load_lds(
                    (const __attribute__((address_space(1))) void*)(src + (size_t)(g0 + lane) * 16),
                    (__attribute__((address_space(3))) void*)(bb + g0 * 16), 16, 0, 0);
            }
        } else {
            #pragma unroll
            for (int i = 0; i < 2; ++i) {
                int g0 = (6 + (wave - 2) * 2 + i) * 64;
                __builtin_amdgcn_global_load_lds(
                    (const __attribute__((address_space(1))) void*)(src + (size_t)(g0 + lane) * 16),
                    (__attribute__((address_space(3))) void*)(bb + g0 * 16), 16, 0, 0);
            }
        }
    };

    f32x16 zero16;
    #pragma unroll
    for (int e = 0; e < 16; ++e) zero16[e] = 0.f;
    f32x16 acc[2];                 // 32 AGPR: wave tile 32 px x 64 och
    acc[0] = zero16; acc[1] = zero16;

    auto mfma_phase = [&](int hc) {
        const char* ab = s_all + A_OFF(hc & 1);
        const char* bb = s_all + B_BASE;
        #pragma unroll
        for (int tap = 0; tap < 9; ++tap) {
            const int kh = tap / 3, kw = tap % 3;
            bf16x8 Bf0 = *(const bf16x8*)(bb + (size_t)((tap * 2 + hw) * 64 +      l31) * 16);
            bf16x8 Bf1 = *(const bf16x8*)(bb + (size_t)((tap * 2 + hw) * 64 + 32 + l31) * 16);
            bf16x8 Af  = *(const bf16x8*)(ab + (wrow + kh) * AROW + swz(wcb + l31 + kw, hw));
            __builtin_amdgcn_s_setprio(1);
            acc[0] = __builtin_amdgcn_mfma_f32_32x32x16_bf16(Af, Bf0, acc[0], 0, 0, 0);
            acc[1] = __builtin_amdgcn_mfma_f32_32x32x16_bf16(Af, Bf1, acc[1], 0, 0, 0);
            __builtin_amdgcn_s_setprio(0);
        }
    };

    // ---- prologue: B(0) DMA'd, A(0) staged, A(1) left in flight ----
    issueB(0);
    issueA(0);
    writeA(0);                     // reg-dep drains A(0); in-order => B(0) too
    issueA(1);
    __builtin_amdgcn_sched_barrier(0);
    asm volatile("s_waitcnt lgkmcnt(0)" ::: "memory");
    __builtin_amdgcn_s_barrier();
    __builtin_amdgcn_sched_barrier(0);

    // ---- main loop: 8 half-chunks of 16 cin, 2 barriers each ----
    #pragma unroll 1
    for (int h = 0; h < 8; ++h) {
        mfma_phase(h);
        __builtin_amdgcn_sched_barrier(0);
        __builtin_amdgcn_s_barrier();            // bar1: A(h),B(h) readers done
        __builtin_amdgcn_sched_barrier(0);
        if (h == 7) break;
        issueB(h + 1);                           // overwrite B (safe after bar1)
        writeA(h + 1);                           // reg-dep wait leaves B in flight
        if (h < 6) {
            issueA(h + 2);                       // stays in flight across barrier
            __builtin_amdgcn_sched_barrier(0);
            // drain own B-DMA, leave own A(h+2) loads outstanding:
            if (e_on) asm volatile("s_waitcnt vmcnt(5) lgkmcnt(0)" ::: "memory");
            else      asm volatile("s_waitcnt vmcnt(4) lgkmcnt(0)" ::: "memory");
        } else {
            __builtin_amdgcn_sched_barrier(0);
            asm volatile("s_waitcnt vmcnt(0) lgkmcnt(0)" ::: "memory");
        }
        __builtin_amdgcn_s_barrier();            // bar2: A(h+1),B(h+1) ready
        __builtin_amdgcn_sched_barrier(0);
    }

    // ---- ReLU -> bf16 X tile in LDS (overlay A region @0), px-swizzled ----
    __bf16* X = (__bf16*)s_all;                  // [256 px][64 ch] = 32 KB
    #pragma unroll
    for (int nt = 0; nt < 2; ++nt) {
        #pragma unroll
        for (int r = 0; r < 16; ++r) {
            float v = fmaxf(acc[nt][r], 0.f);
            int mpix = (r & 3) + 8 * (r >> 2) + 4 * hw;
            int px   = wave * 32 + mpix;
            int chn  = nt * 32 + l31;
            *(__bf16*)((char*)X + px * 128 + ((chn * 2) ^ ((px & 7) << 4))) = (__bf16)v;
        }
    }

    // ---- stage 1x1-head weights + bias (into dead B region) ----
    if (tid < 256) {
        char* s_wc = s_all + WC_BASE;
        float* s_bias = (float*)(s_all + BIAS_BASE);
        int och = tid >> 3;
        int j8  = (tid & 7) * 8;
        float v[8];
        if (och < 20) {
            const float* src = (och < 2)  ? (w_cls + och * 64)
                             : (och < 8)  ? (w_box + (och - 2) * 64)
                             : (och < 16) ? (w_dir + (och - 8) * 64)
                                          : (w_scr + (och - 16) * 64);
            #pragma unroll
            for (int j = 0; j < 8; ++j) v[j] = src[j8 + j];
        } else {
            #pragma unroll
            for (int j = 0; j < 8; ++j) v[j] = 0.f;
        }
        bf16x8 wv;
        #pragma unroll
        for (int j = 0; j < 8; ++j) wv[j] = (__bf16)v[j];
        *(bf16x8*)(s_wc + och * 128 + ((j8 * 2) ^ ((och & 7) << 4))) = wv;
        if (tid < 32) {
            s_bias[tid] = (tid < 2)  ? b_cls[tid]
                        : (tid < 8)  ? b_box[tid - 2]
                        : (tid < 16) ? b_dir[tid - 8]
                        : (tid < 20) ? b_scr[tid - 16] : 0.f;
        }
    }
    __syncthreads();   // wc/bias visible (X strips are wave-local)

    // ---- stage 2: out[och(20->32)][32 px per wave] = Wc @ X, K=64 ----
    const char* s_wc = s_all + WC_BASE;
    const float* s_bias = (const float*)(s_all + BIAS_BASE);
    f32x16 acc2 = zero16;
    #pragma unroll
    for (int ks = 0; ks < 4; ++ks) {
        int ch0 = ks * 16 + hw * 8;
        bf16x8 a2 = *(const bf16x8*)(s_wc + l31 * 128 + ((ch0 * 2) ^ ((l31 & 7) << 4)));
        int px = wave * 32 + l31;
        bf16x8 b2 = *(const bf16x8*)((const char*)X + px * 128 + ((ch0 * 2) ^ ((px & 7) << 4)));
        acc2 = __builtin_amdgcn_mfma_f32_32x32x16_bf16(a2, b2, acc2, 0, 0, 0);
    }

    // ---- epilogue: bias, sigmoid on och 16..19, coalesced stores ----
    const int hrow = h0 + wrow;
    const int wcol = w0 + wcb + l31;
    #pragma unroll
    for (int r = 0; r < 16; ++r) {
        int och = (r & 3) + 8 * (r >> 2) + 4 * hw;
        if (och < 20) {
            float v = acc2[r] + s_bias[och];
            if (och >= 16) v = 1.f / (1.f + __expf(-v));
            out[(((size_t)bz * 20 + och) * 512 + hrow) * 512 + wcol] = v;
        }
    }
}

extern "C" void kernel_launch(void* const* d_in, const int* in_sizes, int n_in,
                              void* d_out, int out_size, void* d_ws, size_t ws_size,
                              hipStream_t stream) {
    const float* feature  = (const float*)d_in[0];
    const float* w_shared = (const float*)d_in[1];
    const float* w_cls = (const float*)d_in[2];
    const float* b_cls = (const float*)d_in[3];
    const float* w_box = (const float*)d_in[4];
    const float* b_box = (const float*)d_in[5];
    const float* w_dir = (const float*)d_in[6];
    const float* b_dir = (const float*)d_in[7];
    const float* w_scr = (const float*)d_in[8];
    const float* b_scr = (const float*)d_in[9];
    float* out = (float*)d_out;
    __bf16* ws3 = (__bf16*)d_ws;   // 8 * 18432 B = 147456 B

    prep_w_kernel<<<288, 256, 0, stream>>>(w_shared, ws3);

    det_main_kernel<<<4096, 512, 0, stream>>>(feature, ws3,
                                              w_cls, b_cls, w_box, b_box,
                                              w_dir, b_dir, w_scr, b_scr, out);
}

// Round 11
// 227.418 us; speedup vs baseline: 1.1486x; 1.0776x over previous
//
#include <hip/hip_runtime.h>
#include <cstdint>
#include <cstddef>

// ---------------------------------------------------------------------------
// DetCenterDense: fused conv3x3(128->64)+ReLU -> 4x conv1x1 heads (20 ch total,
// sigmoid on last 4) over [4,128,512,512] fp32, NCHW. bf16 MFMA implicit GEMM.
// R11: consolidation of R7 (best: 228 us). 256-thr blocks, 12 waves/CU
//      (3 waves/SIMD), A double-buffered LDS + 1-deep reg prefetch, B single
//      LDS buffer via global_load_lds, 2 barriers/hc, counted vmcnt(9) keeps
//      A(h+2) in flight across barriers. Change vs R7: s_setprio removed
//      (T5 is null-to-negative on barrier-lockstep schedules, m190).
// ---------------------------------------------------------------------------

typedef __bf16 bf16x8 __attribute__((ext_vector_type(8)));
typedef float f32x16 __attribute__((ext_vector_type(16)));
typedef float f32x4v __attribute__((ext_vector_type(4)));
typedef float f32x2v __attribute__((ext_vector_type(2)));

#define CHW (512 * 512)

// A-tile LDS swizzle (validated R3-R10): granule 16B at (slot s, octet o):
//   lin = s*32 + o*16 ; byte = lin ^ ((lin>>1)&0x10) ^ ((lin>>2)&0x60)
__device__ __forceinline__ int swz(int s, int o) {
    int lin = (s << 5) | (o << 4);
    return lin ^ ((lin >> 1) & 0x10) ^ ((lin >> 2) & 0x60);
}

// ---------------------------------------------------------------------------
// Prepass: repack w_shared [64][128][3][3] fp32 -> bf16, per-half-chunk
// contiguous: ws3 [hc(8)][tap(9)][hw(2)][och(64)][8 bf16]  (18432 B per hc)
// ---------------------------------------------------------------------------
__global__ void prep_w_kernel(const float* __restrict__ w, __bf16* __restrict__ ws3) {
    int idx = blockIdx.x * 256 + threadIdx.x;
    if (idx >= 64 * 128 * 9) return;
    int tap = idx % 9;
    int cin = (idx / 9) % 128;
    int och = idx / (9 * 128);
    int hc = cin >> 4;
    int hw = (cin >> 3) & 1;
    int j  = cin & 7;
    int dst = (((hc * 9 + tap) * 2 + hw) * 64 + och) * 8 + j;
    ws3[dst] = (__bf16)w[idx];
}

// LDS map (bytes), total 52224 -> 3 blocks/CU (156672 <= 163840):
//   A0 @ 0 [16896]   A1 @ 16896 [16896]   ([4 rows][132 slots x 32B], swz)
//   B  @ 33792 [18432] single buf: [tap 9][hw 2][och 64][8 bf16], linear.
//   After main loop: wc overlays @33792 [4096], bias @37888 [128]; X tile @0.
#define A_OFF(p)  ((p) ? 16896 : 0)
#define B_BASE    33792
#define WC_BASE   33792
#define BIAS_BASE 37888

__global__ __launch_bounds__(256, 3)
void det_main_kernel(const float* __restrict__ feature,
                     const __bf16* __restrict__ ws3,
                     const float* __restrict__ w_cls, const float* __restrict__ b_cls,
                     const float* __restrict__ w_box, const float* __restrict__ b_box,
                     const float* __restrict__ w_dir, const float* __restrict__ b_dir,
                     const float* __restrict__ w_scr, const float* __restrict__ b_scr,
                     float* __restrict__ out) {
    __shared__ __align__(1024) char s_all[52224];

    const int tid  = threadIdx.x;
    const int lane = tid & 63;
    const int wave = tid >> 6;
    const int l31  = lane & 31;
    const int hw   = lane >> 5;
    const int wrow = wave >> 1;
    const int wcb  = (wave & 1) * 64;

    // XCD-aware decode: 4096 blocks -> 8 chunks of 512; vertical neighbors
    // (sharing halo rows) schedule-adjacent within an XCD.
    const int bid = blockIdx.x;
    const int wg  = (bid & 7) * 512 + (bid >> 3);
    const int ck  = wg >> 9;
    const int bz  = ck >> 1;
    const int rem = wg & 511;
    const int h0  = (rem >> 1) * 2;
    const int w0  = ((ck & 1) * 2 + (rem & 1)) * 128;

    // ---- staging roles (R4-validated) ----
    // main: thread covers (cin octet m_hw, slot-quad m_q, row m_row): 8 dwordx4
    const int m_hw  = tid & 1;
    const int m_q   = (tid >> 1) & 31;
    const int m_row = tid >> 6;
    const int m_h   = h0 - 1 + m_row;
    const bool m_ok = (unsigned)m_h < 512u;
    const float* m_base = feature + (size_t)(bz * 128 + m_hw * 8) * CHW
                        + (size_t)(m_ok ? m_h : 0) * 512 + (w0 + 4 * m_q);
    // edge: even lanes of every wave (uniform per-wave instr count): 1 dwordx2
    const bool e_on = (tid & 1) == 0;
    const int e_idx = tid >> 1;
    const int e_ee  = (e_idx >> 6) & 1;
    const int e_row = (e_idx >> 4) & 3;
    const int e_cin = e_idx & 15;
    const int e_h   = h0 - 1 + e_row;
    const int e_w   = e_ee ? (w0 + 128) : (w0 - 2);
    const bool e_ok = ((unsigned)e_h < 512u) && ((unsigned)e_w < 511u);
    const float* e_base = feature + (size_t)(bz * 128 + e_cin) * CHW
                        + (size_t)(e_ok ? e_h : 0) * 512 + (e_ok ? e_w : 0);

    f32x4v R[8];      // 1-deep A prefetch (32 VGPR)
    f32x2v E;

    // issue A-loads for half-chunk hc: ALWAYS 9 vmem instrs per wave.
    auto issueA = [&](int hc) {
        const float* p = m_base + (size_t)(hc * 16) * CHW;
        #pragma unroll
        for (int j = 0; j < 8; ++j) R[j] = *(const f32x4v*)(p + (size_t)j * CHW);
        if (e_on) E = *(const f32x2v*)(e_base + (size_t)(hc * 16) * CHW);
    };

    // convert + ds_write into A-buf[hc&1]; zero OOB here (no vmem).
    auto writeA = [&](int hc) {
        char* ab = s_all + A_OFF(hc & 1);
        #pragma unroll
        for (int k = 0; k < 4; ++k) {
            bf16x8 g;
            #pragma unroll
            for (int j = 0; j < 8; ++j) g[j] = (__bf16)(m_ok ? R[j][k] : 0.f);
            *(bf16x8*)(ab + m_row * 4224 + swz(2 + 4 * m_q + k, m_hw)) = g;
        }
        if (e_on) {
            char* b2 = ab + e_row * 4224 + (e_cin & 7) * 2;
            int s0 = e_ee ? 130 : 0;
            *(__bf16*)(b2 + swz(s0,     e_cin >> 3)) = (__bf16)(e_ok ? E[0] : 0.f);
            *(__bf16*)(b2 + swz(s0 + 1, e_cin >> 3)) = (__bf16)(e_ok ? E[1] : 0.f);
        }
    };

    // async global->LDS of hc's weights into single B buffer (1152 x 16B).
    auto issueB = [&](int hc) {
        char* bb = s_all + B_BASE;
        const char* src = (const char*)ws3 + hc * 18432;
        #pragma unroll
        for (int i = 0; i < 4; ++i) {
            int g0 = i * 256 + wave * 64;
            __builtin_amdgcn_global_load_lds(
                (const __attribute__((address_space(1))) void*)(src + (size_t)(g0 + lane) * 16),
                (__attribute__((address_space(3))) void*)(bb + g0 * 16), 16, 0, 0);
        }
        if (wave < 2) {
            int g0 = 1024 + wave * 64;
            __builtin_amdgcn_global_load_lds(
                (const __attribute__((address_space(1))) void*)(src + (size_t)(g0 + lane) * 16),
                (__attribute__((address_space(3))) void*)(bb + g0 * 16), 16, 0, 0);
        }
    };

    f32x16 zero16;
    #pragma unroll
    for (int e = 0; e < 16; ++e) zero16[e] = 0.f;
    f32x16 acc[2][2];
    acc[0][0] = zero16; acc[0][1] = zero16; acc[1][0] = zero16; acc[1][1] = zero16;

    auto mfma_phase = [&](int hc) {
        const char* ab = s_all + A_OFF(hc & 1);
        const char* bb = s_all + B_BASE;
        #pragma unroll
        for (int tap = 0; tap < 9; ++tap) {
            const int kh = tap / 3, kw = tap % 3;
            bf16x8 Bf0 = *(const bf16x8*)(bb + (size_t)((tap * 2 + hw) * 64 +      l31) * 16);
            bf16x8 Bf1 = *(const bf16x8*)(bb + (size_t)((tap * 2 + hw) * 64 + 32 + l31) * 16);
            bf16x8 Af0 = *(const bf16x8*)(ab + (wrow + kh) * 4224 + swz(wcb +      l31 + kw + 1, hw));
            bf16x8 Af1 = *(const bf16x8*)(ab + (wrow + kh) * 4224 + swz(wcb + 32 + l31 + kw + 1, hw));
            acc[0][0] = __builtin_amdgcn_mfma_f32_32x32x16_bf16(Af0, Bf0, acc[0][0], 0, 0, 0);
            acc[0][1] = __builtin_amdgcn_mfma_f32_32x32x16_bf16(Af0, Bf1, acc[0][1], 0, 0, 0);
            acc[1][0] = __builtin_amdgcn_mfma_f32_32x32x16_bf16(Af1, Bf0, acc[1][0], 0, 0, 0);
            acc[1][1] = __builtin_amdgcn_mfma_f32_32x32x16_bf16(Af1, Bf1, acc[1][1], 0, 0, 0);
        }
    };

    // ---- prologue: B(0) DMA'd, A(0) staged, A(1) left in flight ----
    issueB(0);
    issueA(0);
    writeA(0);                     // reg-deps drain A(0); in-order => B(0) too
    issueA(1);
    __builtin_amdgcn_sched_barrier(0);
    asm volatile("s_waitcnt vmcnt(9) lgkmcnt(0)" ::: "memory");  // A(1) in flight
    __builtin_amdgcn_s_barrier();
    __builtin_amdgcn_sched_barrier(0);

    // ---- main loop: 8 half-chunks of 16 cin, 2 barriers each ----
    #pragma unroll 1
    for (int h = 0; h < 8; ++h) {
        mfma_phase(h);
        __builtin_amdgcn_sched_barrier(0);
        __builtin_amdgcn_s_barrier();            // bar1: A(h),B(h) readers done
        __builtin_amdgcn_sched_barrier(0);
        if (h == 7) break;
        issueB(h + 1);                           // overwrite B (safe after bar1)
        writeA(h + 1);                           // into A-buf[(h+1)&1]
        if (h < 6) issueA(h + 2);
        if (h < 6) asm volatile("s_waitcnt vmcnt(9) lgkmcnt(0)" ::: "memory");
        else       asm volatile("s_waitcnt vmcnt(0) lgkmcnt(0)" ::: "memory");
        __builtin_amdgcn_s_barrier();            // bar2: A(h+1),B(h+1) ready
        __builtin_amdgcn_sched_barrier(0);
    }

    // ---- ReLU -> bf16 X tile in LDS (reuse A region @0), px-XOR swizzled ----
    __bf16* X = (__bf16*)s_all;                  // [256 px][64 ch] = 32 KB
    #pragma unroll
    for (int mt = 0; mt < 2; ++mt) {
        #pragma unroll
        for (int nt = 0; nt < 2; ++nt) {
            #pragma unroll
            for (int r = 0; r < 16; ++r) {
                float v = fmaxf(acc[mt][nt][r], 0.f);
                int mrow = (r & 3) + 8 * (r >> 2) + 4 * hw;
                int pxb  = wave * 64 + mt * 32 + mrow;
                int chn  = nt * 32 + l31;
                *(__bf16*)((char*)X + pxb * 128 + ((chn * 2) ^ ((pxb & 7) << 4))) = (__bf16)v;
            }
        }
    }

    // ---- stage 1x1-head weights + bias (post-loop, into dead B region) ----
    {
        char* s_wc = s_all + WC_BASE;
        float* s_bias = (float*)(s_all + BIAS_BASE);
        int och = tid >> 3;
        int j8  = (tid & 7) * 8;
        float v[8];
        if (och < 20) {
            const float* src = (och < 2)  ? (w_cls + och * 64)
                             : (och < 8)  ? (w_box + (och - 2) * 64)
                             : (och < 16) ? (w_dir + (och - 8) * 64)
                                          : (w_scr + (och - 16) * 64);
            #pragma unroll
            for (int j = 0; j < 8; ++j) v[j] = src[j8 + j];
        } else {
            #pragma unroll
            for (int j = 0; j < 8; ++j) v[j] = 0.f;
        }
        bf16x8 wv;
        #pragma unroll
        for (int j = 0; j < 8; ++j) wv[j] = (__bf16)v[j];
        *(bf16x8*)(s_wc + och * 128 + ((j8 * 2) ^ ((och & 7) << 4))) = wv;
        if (tid < 32) {
            s_bias[tid] = (tid < 2)  ? b_cls[tid]
                        : (tid < 8)  ? b_box[tid - 2]
                        : (tid < 16) ? b_dir[tid - 8]
                        : (tid < 20) ? b_scr[tid - 16] : 0.f;
        }
    }
    __syncthreads();   // wc/bias visible to all waves (X is wave-local)

    // ---- stage 2: out[och(20->32)][px] = Wc @ X, K=64 ----
    const char* s_wc = s_all + WC_BASE;
    const float* s_bias = (const float*)(s_all + BIAS_BASE);
    f32x16 acc2[2];
    acc2[0] = zero16; acc2[1] = zero16;
    #pragma unroll
    for (int ks = 0; ks < 4; ++ks) {
        int ch0 = ks * 16 + hw * 8;
        bf16x8 a2 = *(const bf16x8*)(s_wc + l31 * 128 + ((ch0 * 2) ^ ((l31 & 7) << 4)));
        #pragma unroll
        for (int nt = 0; nt < 2; ++nt) {
            int pxb = wave * 64 + nt * 32 + l31;
            bf16x8 b2 = *(const bf16x8*)((const char*)X + pxb * 128 + ((ch0 * 2) ^ ((pxb & 7) << 4)));
            acc2[nt] = __builtin_amdgcn_mfma_f32_32x32x16_bf16(a2, b2, acc2[nt], 0, 0, 0);
        }
    }

    // ---- epilogue: bias, sigmoid on och 16..19, coalesced stores ----
    const int h = h0 + wrow;
    #pragma unroll
    for (int nt = 0; nt < 2; ++nt) {
        int wg2 = w0 + wcb + nt * 32 + l31;
        #pragma unroll
        for (int r = 0; r < 16; ++r) {
            int och = (r & 3) + 8 * (r >> 2) + 4 * hw;
            if (och < 20) {
                float v = acc2[nt][r] + s_bias[och];
                if (och >= 16) v = 1.f / (1.f + __expf(-v));
                out[(((size_t)bz * 20 + och) * 512 + h) * 512 + wg2] = v;
            }
        }
    }
}

extern "C" void kernel_launch(void* const* d_in, const int* in_sizes, int n_in,
                              void* d_out, int out_size, void* d_ws, size_t ws_size,
                              hipStream_t stream) {
    const float* feature  = (const float*)d_in[0];
    const float* w_shared = (const float*)d_in[1];
    const float* w_cls = (const float*)d_in[2];
    const float* b_cls = (const float*)d_in[3];
    const float* w_box = (const float*)d_in[4];
    const float* b_box = (const float*)d_in[5];
    const float* w_dir = (const float*)d_in[6];
    const float* b_dir = (const float*)d_in[7];
    const float* w_scr = (const float*)d_in[8];
    const float* b_scr = (const float*)d_in[9];
    float* out = (float*)d_out;
    __bf16* ws3 = (__bf16*)d_ws;   // 8 * 18432 B = 147456 B

    prep_w_kernel<<<288, 256, 0, stream>>>(w_shared, ws3);

    det_main_kernel<<<4096, 256, 0, stream>>>(feature, ws3,
                                              w_cls, b_cls, w_box, b_box,
                                              w_dir, b_dir, w_scr, b_scr, out);
}